// Round 2
// baseline (240.776 us; speedup 1.0000x reference)
//
#include <hip/hip_runtime.h>
#include <hip/hip_bf16.h>

// x[1,32,14,14,14] -> trilinear upsample(224, align_corners) -> 1x1x1 conv
// (32->4) -> softmax(dim=1). Output [1,4,224,224,224] fp32 (~180 MB).
//
// Conv commutes with interpolation (both linear, interp weights sum to 1),
// so contract 32->4 channels on the 14^3 grid, then upsample 4 channels with
// fused softmax. Logits are pre-scaled by log2(e) so the softmax needs no
// per-voxel scaling; no max-subtraction (|logits| < ~10, exp2f-safe in fp32).
//
// upsample kernel: 1 thread = 16 consecutive w-voxels (span 15*13/223 = 0.874
// < 1 source cell => at most 3 source knots). Branchless piecewise lerp:
//   v(u) = g0 + min(u,1)*d10 + max(u-1,0)*d21,  u = posw - iw0.
// z (44 KB) stays L1/L2-resident - no LDS, no barrier, no occupancy cap.

#define NSP 2744            // 14^3
#define NV  11239424u       // 224^3
#define RATIO 0.0582959641255605381166f   // 13/223

// ---------------- Kernel 1: z[s] = log2(e)*(W @ x + b), channels packed -----
__global__ __launch_bounds__(256) void conv_small(
    const float* __restrict__ x,   // [32][2744]
    const float* __restrict__ W,   // [4][32]
    const float* __restrict__ b,   // [4]
    float4* __restrict__ z)        // [2744]
{
    int s = blockIdx.x * 256 + threadIdx.x;
    if (s >= NSP) return;
    float a0 = b[0], a1 = b[1], a2 = b[2], a3 = b[3];
#pragma unroll
    for (int c = 0; c < 32; ++c) {
        float xv = x[c * NSP + s];
        a0 = fmaf(W[c],      xv, a0);
        a1 = fmaf(W[32 + c], xv, a1);
        a2 = fmaf(W[64 + c], xv, a2);
        a3 = fmaf(W[96 + c], xv, a3);
    }
    const float LOG2E = 1.44269504088896340736f;
    z[s] = make_float4(a0 * LOG2E, a1 * LOG2E, a2 * LOG2E, a3 * LOG2E);
}

// ---------------- Kernel 2: upsample + softmax ------------------------------
__device__ __forceinline__ float4 bilerp4(const float4* __restrict__ z,
                                          int b00, int iw,
                                          float c00, float c01, float c10, float c11)
{
    float4 A = z[b00 + iw], B = z[b00 + 14 + iw], C = z[b00 + 196 + iw], D = z[b00 + 210 + iw];
    float4 r;
    r.x = fmaf(c11, D.x, fmaf(c10, C.x, fmaf(c01, B.x, c00 * A.x)));
    r.y = fmaf(c11, D.y, fmaf(c10, C.y, fmaf(c01, B.y, c00 * A.y)));
    r.z = fmaf(c11, D.z, fmaf(c10, C.z, fmaf(c01, B.z, c00 * A.z)));
    r.w = fmaf(c11, D.w, fmaf(c10, C.w, fmaf(c01, B.w, c00 * A.w)));
    return r;
}

__global__ __launch_bounds__(256) void upsample_softmax(
    const float4* __restrict__ z,   // [14][14][14] of float4 (4 channels)
    float* __restrict__ out)        // [4][224][224][224]
{
    // 702,464 threads total = 2744 blocks x 256; thread = (row, 16-voxel seg)
    unsigned gid = blockIdx.x * 256u + threadIdx.x;
    unsigned seg = gid % 14u;        // 14 segments of 16 voxels per row
    unsigned row = gid / 14u;        // d*224 + h
    unsigned hh  = row % 224u;
    unsigned dd  = row / 224u;

    float posd = (float)dd * RATIO;
    int   i0d  = min((int)posd, 12);
    float wd   = posd - (float)i0d;
    float posh = (float)hh * RATIO;
    int   i0h  = min((int)posh, 12);
    float wh   = posh - (float)i0h;

    // bilinear (d,h) weights
    float c11 = wd * wh;
    float c10 = wd - c11;
    float c01 = wh - c11;
    float c00 = 1.0f - wd - wh + c11;
    int b00 = (i0d * 14 + i0h) * 14;

    int   wb    = (int)seg * 16;
    float posw0 = (float)wb * RATIO;
    int   iw0   = min((int)posw0, 12);
    float u0    = posw0 - (float)iw0;

    float4 g0 = bilerp4(z, b00, iw0,              c00, c01, c10, c11);
    float4 g1 = bilerp4(z, b00, iw0 + 1,          c00, c01, c10, c11);
    float4 g2 = bilerp4(z, b00, min(iw0 + 2, 13), c00, c01, c10, c11);

    float4 d10, d21;
    d10.x = g1.x - g0.x; d10.y = g1.y - g0.y; d10.z = g1.z - g0.z; d10.w = g1.w - g0.w;
    d21.x = g2.x - g1.x; d21.y = g2.y - g1.y; d21.z = g2.z - g1.z; d21.w = g2.w - g1.w;

    unsigned sbase = row * 224u + (unsigned)wb;
#pragma unroll
    for (int q = 0; q < 4; ++q) {
        float och[4][4];   // [channel][voxel-in-quad]
#pragma unroll
        for (int jj = 0; jj < 4; ++jj) {
            float u  = fmaf((float)(q * 4 + jj), RATIO, u0);
            float u1 = fminf(u, 1.0f);
            float u2 = fmaxf(u - 1.0f, 0.0f);
            // logits already in log2 domain
            float t0 = fmaf(u2, d21.x, fmaf(u1, d10.x, g0.x));
            float t1 = fmaf(u2, d21.y, fmaf(u1, d10.y, g0.y));
            float t2 = fmaf(u2, d21.z, fmaf(u1, d10.z, g0.z));
            float t3 = fmaf(u2, d21.w, fmaf(u1, d10.w, g0.w));
            float e0 = exp2f(t0), e1 = exp2f(t1), e2 = exp2f(t2), e3 = exp2f(t3);
            float s   = (e0 + e1) + (e2 + e3);
            float inv = __builtin_amdgcn_rcpf(s);
            och[0][jj] = e0 * inv;
            och[1][jj] = e1 * inv;
            och[2][jj] = e2 * inv;
            och[3][jj] = e3 * inv;
        }
        unsigned sidx = sbase + (unsigned)(q * 4);
        *(float4*)(out + 0u * NV + sidx) = make_float4(och[0][0], och[0][1], och[0][2], och[0][3]);
        *(float4*)(out + 1u * NV + sidx) = make_float4(och[1][0], och[1][1], och[1][2], och[1][3]);
        *(float4*)(out + 2u * NV + sidx) = make_float4(och[2][0], och[2][1], och[2][2], och[2][3]);
        *(float4*)(out + 3u * NV + sidx) = make_float4(och[3][0], och[3][1], och[3][2], och[3][3]);
    }
}

extern "C" void kernel_launch(void* const* d_in, const int* in_sizes, int n_in,
                              void* d_out, int out_size, void* d_ws, size_t ws_size,
                              hipStream_t stream) {
    const float* x = (const float*)d_in[0];   // [1,32,14,14,14]
    const float* W = (const float*)d_in[1];   // [4,32]
    const float* b = (const float*)d_in[2];   // [4]
    float* out = (float*)d_out;               // [1,4,224,224,224]
    float4* z = (float4*)d_ws;                // 2744 float4 = 43,904 B scratch

    conv_small<<<(NSP + 255) / 256, 256, 0, stream>>>(x, W, b, z);
    upsample_softmax<<<702464u / 256u, 256, 0, stream>>>(z, out);
}

// Round 4
// 191.287 us; speedup vs baseline: 1.2587x; 1.2587x over previous
//
#include <hip/hip_runtime.h>
#include <hip/hip_bf16.h>

// x[1,32,14,14,14] -> trilinear upsample(224, align_corners) -> 1x1x1 conv
// (32->4) -> softmax(dim=1). Output [1,4,224,224,224] fp32 (~180 MB).
//
// Conv commutes with interpolation (both linear, weights sum to 1), so
// contract 32->4 on the 14^3 grid, then upsample 4 channels + fused softmax.
// Logits pre-scaled by log2(e); softmax via exp2, no max-subtraction
// (|logits| < ~10, fp32-safe; verified absmax 0.0039 << 0.019 threshold).
//
// Mapping (round-1, proven): thread = 4 consecutive w voxels; lane-consecutive
// threads -> contiguous 1KB-per-wave float4 stores per channel plane.
// Round-2's 16-voxel strided mapping broke store coalescing (-30%): reverted.
// This round: nontemporal stores (streaming 180MB, never re-read) via native
// Clang vector type (HIP float4 class is rejected by the builtin).

#define NSP 2744            // 14^3
#define NV  11239424u       // 224^3
#define RATIO 0.0582959641255605381166f   // 13/223

typedef float v4f __attribute__((ext_vector_type(4)));

// ---------------- Kernel 1: z[s] = log2(e)*(W @ x + b), channels packed -----
__global__ __launch_bounds__(256) void conv_small(
    const float* __restrict__ x,   // [32][2744]
    const float* __restrict__ W,   // [4][32]
    const float* __restrict__ b,   // [4]
    v4f* __restrict__ z)           // [2744]
{
    int s = blockIdx.x * 256 + threadIdx.x;
    if (s >= NSP) return;
    float a0 = b[0], a1 = b[1], a2 = b[2], a3 = b[3];
#pragma unroll
    for (int c = 0; c < 32; ++c) {
        float xv = x[c * NSP + s];
        a0 = fmaf(W[c],      xv, a0);
        a1 = fmaf(W[32 + c], xv, a1);
        a2 = fmaf(W[64 + c], xv, a2);
        a3 = fmaf(W[96 + c], xv, a3);
    }
    const float LOG2E = 1.44269504088896340736f;
    v4f r; r.x = a0 * LOG2E; r.y = a1 * LOG2E; r.z = a2 * LOG2E; r.w = a3 * LOG2E;
    z[s] = r;
}

// ---------------- Kernel 2: upsample + softmax ------------------------------
__device__ __forceinline__ v4f bilerp4(const v4f* __restrict__ zs,
                                       int b00, int iw,
                                       float c00, float c01, float c10, float c11)
{
    v4f A = zs[b00 + iw], B = zs[b00 + 14 + iw];
    v4f C = zs[b00 + 196 + iw], D = zs[b00 + 210 + iw];
    v4f r;
    r.x = fmaf(c11, D.x, fmaf(c10, C.x, fmaf(c01, B.x, c00 * A.x)));
    r.y = fmaf(c11, D.y, fmaf(c10, C.y, fmaf(c01, B.y, c00 * A.y)));
    r.z = fmaf(c11, D.z, fmaf(c10, C.z, fmaf(c01, B.z, c00 * A.z)));
    r.w = fmaf(c11, D.w, fmaf(c10, C.w, fmaf(c01, B.w, c00 * A.w)));
    return r;
}

__global__ __launch_bounds__(512) void upsample_softmax(
    const v4f* __restrict__ z,      // [14][14][14] of v4f (4 channels)
    float* __restrict__ out)        // [4][224][224][224]
{
    __shared__ v4f zs[NSP];         // 43,904 B -> 3 blocks/CU (LDS-limited)
    for (int k = threadIdx.x; k < NSP; k += 512) zs[k] = z[k];
    __syncthreads();

    // 2,809,856 threads = 5488 blocks x 512; thread = 4 consecutive w voxels
    unsigned gid = blockIdx.x * 512u + threadIdx.x;
    unsigned w4  = gid % 56u;        // quad index within row
    unsigned row = gid / 56u;        // d*224 + h
    unsigned hh  = row % 224u;
    unsigned dd  = row / 224u;

    float posd = (float)dd * RATIO;
    int   i0d  = min((int)posd, 12);
    float wd   = posd - (float)i0d;
    float posh = (float)hh * RATIO;
    int   i0h  = min((int)posh, 12);
    float wh   = posh - (float)i0h;

    float c11 = wd * wh;
    float c10 = wd - c11;
    float c01 = wh - c11;
    float c00 = 1.0f - wd - wh + c11;
    int b00 = (i0d * 14 + i0h) * 14;

    int   wb    = (int)w4 * 4;
    float posw0 = (float)wb * RATIO;
    int   iw0   = min((int)posw0, 12);
    float u0    = posw0 - (float)iw0;

    v4f g0 = bilerp4(zs, b00, iw0,              c00, c01, c10, c11);
    v4f g1 = bilerp4(zs, b00, iw0 + 1,          c00, c01, c10, c11);
    v4f g2 = bilerp4(zs, b00, min(iw0 + 2, 13), c00, c01, c10, c11);

    v4f d10 = g1 - g0;
    v4f d21 = g2 - g1;

    float och[4][4];   // [channel][voxel]
#pragma unroll
    for (int j = 0; j < 4; ++j) {
        float u  = fmaf((float)j, RATIO, u0);
        float u1 = fminf(u, 1.0f);
        float u2 = fmaxf(u - 1.0f, 0.0f);
        // logits already in log2 domain
        float t0 = fmaf(u2, d21.x, fmaf(u1, d10.x, g0.x));
        float t1 = fmaf(u2, d21.y, fmaf(u1, d10.y, g0.y));
        float t2 = fmaf(u2, d21.z, fmaf(u1, d10.z, g0.z));
        float t3 = fmaf(u2, d21.w, fmaf(u1, d10.w, g0.w));
        float e0 = exp2f(t0), e1 = exp2f(t1), e2 = exp2f(t2), e3 = exp2f(t3);
        float s   = (e0 + e1) + (e2 + e3);
        float inv = __builtin_amdgcn_rcpf(s);
        och[0][j] = e0 * inv;
        och[1][j] = e1 * inv;
        och[2][j] = e2 * inv;
        och[3][j] = e3 * inv;
    }

    // transpose to per-channel v4f; coalesced nontemporal streaming stores
    unsigned sidx = row * 224u + (unsigned)wb;
    v4f o0 = { och[0][0], och[0][1], och[0][2], och[0][3] };
    v4f o1 = { och[1][0], och[1][1], och[1][2], och[1][3] };
    v4f o2 = { och[2][0], och[2][1], och[2][2], och[2][3] };
    v4f o3 = { och[3][0], och[3][1], och[3][2], och[3][3] };
    __builtin_nontemporal_store(o0, (v4f*)(out + 0u * NV + sidx));
    __builtin_nontemporal_store(o1, (v4f*)(out + 1u * NV + sidx));
    __builtin_nontemporal_store(o2, (v4f*)(out + 2u * NV + sidx));
    __builtin_nontemporal_store(o3, (v4f*)(out + 3u * NV + sidx));
}

extern "C" void kernel_launch(void* const* d_in, const int* in_sizes, int n_in,
                              void* d_out, int out_size, void* d_ws, size_t ws_size,
                              hipStream_t stream) {
    const float* x = (const float*)d_in[0];   // [1,32,14,14,14]
    const float* W = (const float*)d_in[1];   // [4,32]
    const float* b = (const float*)d_in[2];   // [4]
    float* out = (float*)d_out;               // [1,4,224,224,224]
    v4f* z = (v4f*)d_ws;                      // 2744 v4f = 43,904 B scratch

    conv_small<<<(NSP + 255) / 256, 256, 0, stream>>>(x, W, b, z);
    upsample_softmax<<<5488, 512, 0, stream>>>(z, out);
}